// Round 7
// baseline (36.399 us; speedup 1.0000x reference)
//
#include <hip/hip_runtime.h>
#include <math.h>

#define BATCH 8
#define TLEN  512
#define DDIM  512
#define TOUT  608   // 512 + 96
#define KSEL  32
#define DT    8     // d columns per block

#define TWO_PI_OVER_512 0.0122718463030851562f

// 16-point DFT twiddles (exact constants), e^{-2pi i n/16} = CC[n] - i*SS[n]
__device__ __constant__ const float CC16[16] = {
     1.f,  0.92387953251128674f,  0.70710678118654752f,  0.38268343236508977f,
     0.f, -0.38268343236508977f, -0.70710678118654752f, -0.92387953251128674f,
    -1.f, -0.92387953251128674f, -0.70710678118654752f, -0.38268343236508977f,
     0.f,  0.38268343236508977f,  0.70710678118654752f,  0.92387953251128674f };
__device__ __constant__ const float SS16[16] = {
     0.f,  0.38268343236508977f,  0.70710678118654752f,  0.92387953251128674f,
     1.f,  0.92387953251128674f,  0.70710678118654752f,  0.38268343236508977f,
     0.f, -0.38268343236508977f, -0.70710678118654752f, -0.92387953251128674f,
    -1.f, -0.92387953251128674f, -0.70710678118654752f, -0.38268343236508977f };

// ---------------------------------------------------------------------------
// One block = (b, 8-d tile), 512 threads (8 waves) for 4 waves/SIMD occupancy.
//   A: radix-16 DFT (t = a + 32c); thread = (a, d, q-half) -> all 16 q rows
//      in LDS after one barrier (x loaded redundantly by the two half-threads)
//   B: 32-point combine, thread = (ahalf, d, kk0..31); full 256-m spectrum
//   topk: one wave per column; binary search on |X|^2 bits + ballot compaction
//   synth: 8 t per thread, 4-way ILP rotation chains; t in [0,512) with rows
//          0..95 duplicated to 512..607 (signal is exactly 512-periodic)
// LDS ~54.5 KB -> 2 blocks/CU = 16 waves/CU.
// ---------------------------------------------------------------------------
__global__ __launch_bounds__(512, 4) void fourier_fused(const float* __restrict__ x,
                                                        float* __restrict__ out) {
    __shared__ float2 Xl[DT][257];                       // 16,448 B
    __shared__ __align__(16) unsigned char uni[38016];   // ysr|ysi  /  selL+tab2
    float*  ysr  = (float*)uni;                          // [16][33][9]
    float*  ysi  = ysr + 16 * 33 * 9;
    float4* selL = (float4*)uni;                         // [8][stride 33]
    float2* tab2 = (float2*)(uni + 8 * 33 * 16);         // [512], offset 4224

    const int tid = threadIdx.x;
    const int bid = blockIdx.x;          // 8b x 64 d-tiles
    const int b   = bid >> 6;
    const int d0  = (bid & 63) * DT;

    // ---- stage A: thread = (aA, dA, h) computes q rows [8h, 8h+8) ----
    {
        const int h   = tid >> 8;        // q-half
        const int rem = tid & 255;
        const int aA  = rem >> 3;        // 0..31
        const int dA  = rem & 7;
        const float* xb = x + ((size_t)b * TLEN + aA) * DDIM + d0 + dA;
        float xv[16];
        #pragma unroll
        for (int c = 0; c < 16; ++c)
            xv[c] = xb[(size_t)c * 32 * DDIM];

        #pragma unroll
        for (int qn = 0; qn < 8; ++qn) {
            const int q = qn + 8 * h;
            float sr = 0.f, si = 0.f;
            #pragma unroll
            for (int c = 0; c < 16; ++c) {
                const int n = (c * q) & 15;
                sr = fmaf(xv[c],  CC16[n], sr);
                si = fmaf(xv[c], -SS16[n], si);
            }
            ysr[(q * 33 + aA) * 9 + dA] = sr;
            ysi[(q * 33 + aA) * 9 + dA] = si;
        }
    }
    __syncthreads();

    // ---- stage B: thread = (ahalf, dB, kk) ----
    {
        const int ahalf = tid & 1;
        const int dB    = (tid >> 1) & 7;
        const int kk    = tid >> 4;      // 0..31
        const int qq    = kk & 15;

        float Pr, Pi;
        if (ahalf == 0) { Pr = 1.f; Pi = 0.f; }
        else {
            float s, c;
            sincosf((float)((16 * kk) & 511) * TWO_PI_OVER_512, &s, &c);
            Pr = c; Pi = -s;
        }
        float sts, stc;
        sincosf((float)kk * TWO_PI_OVER_512, &sts, &stc);  // e^{-2pi i kk/512}

        float ar[8] = {}, ai[8] = {};
        #pragma unroll
        for (int aa = 0; aa < 16; ++aa) {
            const int arow = ahalf * 16 + aa;     // (arow*u)&15 == (aa*u)&15
            float Yr = ysr[(qq * 33 + arow) * 9 + dB];
            float Yi = ysi[(qq * 33 + arow) * 9 + dB];
            float zr = Yr * Pr - Yi * Pi;
            float zi = Yr * Pi + Yi * Pr;
            #pragma unroll
            for (int u = 0; u < 8; ++u) {
                const int n = (aa * u) & 15;
                ar[u] = fmaf(zr, CC16[n], fmaf(zi,  SS16[n], ar[u]));
                ai[u] = fmaf(zi, CC16[n], fmaf(-zr, SS16[n], ai[u]));
            }
            float npr = fmaf(Pr, stc,  Pi * sts);
            Pi        = fmaf(Pi, stc, -Pr * sts);
            Pr        = npr;
        }

        // combine a-halves (partner lane = tid^1 flips ahalf)
        #pragma unroll
        for (int u = 0; u < 8; ++u) {
            ar[u] += __shfl_xor(ar[u], 1);
            ai[u] += __shfl_xor(ai[u], 1);
        }
        #pragma unroll
        for (int v = 0; v < 4; ++v) {
            const int u = ahalf * 4 + v;
            Xl[dB][kk + 32 * u] = make_float2(ar[u], ai[u]);
        }
    }
    __syncthreads();   // Xl complete; ys dead (union reuse OK)

    // ---- topk: wave w handles column w (+ tab2 init into the union) ----
    {
        {
            float s, c;
            sincosf((float)tid * TWO_PI_OVER_512, &s, &c);
            tab2[tid] = make_float2(c, s);
        }

        const int l  = tid & 63;
        const int dd = tid >> 6;         // 0..7
        const unsigned long long below = ((unsigned long long)1 << l) - 1;

        float zr[4], zi[4];
        unsigned vb[4];
        int mm[4];
        #pragma unroll
        for (int s = 0; s < 4; ++s) {
            int m = 1 + l + 64 * s;
            mm[s] = m;
            if (m <= 255) {
                float2 z = Xl[dd][m];
                zr[s] = z.x; zi[s] = z.y;
                vb[s] = __float_as_uint(fmaf(z.x, z.x, z.y * z.y));
            } else { zr[s] = 0.f; zi[s] = 0.f; vb[s] = 0u; }
        }

        unsigned tau = 0;
        for (int bit = 30; bit >= 0; --bit) {
            unsigned cand = tau | (1u << bit);
            int cnt = __popcll(__ballot(vb[0] >= cand))
                    + __popcll(__ballot(vb[1] >= cand))
                    + __popcll(__ballot(vb[2] >= cand))
                    + __popcll(__ballot(vb[3] >= cand));
            if (cnt >= KSEL) tau = cand;
        }

        unsigned long long bgt[4], beq[4];
        int cgt = 0;
        #pragma unroll
        for (int s = 0; s < 4; ++s) {
            bgt[s] = __ballot(vb[s] > tau);
            beq[s] = __ballot(vb[s] == tau);
            cgt += __popcll(bgt[s]);
        }
        const int need = KSEL - cgt;     // ties taken at == tau

        int bg = 0, be = 0;
        #pragma unroll
        for (int s = 0; s < 4; ++s) {
            if (vb[s] > tau) {
                int slot = bg + __popcll(bgt[s] & below);
                selL[dd * 33 + slot] = make_float4(__int_as_float(mm[s]), zr[s], zi[s], 0.f);
            } else if (vb[s] == tau) {
                int r = be + __popcll(beq[s] & below);
                if (r < need)
                    selL[dd * 33 + cgt + r] = make_float4(__int_as_float(mm[s]), zr[s], zi[s], 0.f);
            }
            bg += __popcll(bgt[s]);
            be += __popcll(beq[s]);
        }
    }
    __syncthreads();   // selL + tab2 ready

    // ---- synth: thread = (dd, 8-t chunk); rows 0..95 also stored at +512 ----
    {
        const int dd = tid & 7;
        const int tc = tid >> 3;         // 0..63
        const int t0 = tc * 8;
        const float sc = 2.0f / 512.0f;

        float acc[8] = {};

        #pragma unroll 2
        for (int g = 0; g < 8; ++g) {
            float zr_[4], zi_[4], ex_[4], ey_[4];
            #pragma unroll
            for (int i = 0; i < 4; ++i) {
                float4 sv = selL[dd * 33 + g * 4 + i];
                int   m  = __float_as_int(sv.x);
                float a  = sv.y * sc;
                float gg = sv.z * sc;
                float2 wv = tab2[(m * t0) & 511];
                float2 ev = tab2[m];
                zr_[i] = a * wv.x - gg * wv.y;
                zi_[i] = a * wv.y + gg * wv.x;
                ex_[i] = ev.x; ey_[i] = ev.y;
            }
            #pragma unroll
            for (int t = 0; t < 8; ++t) {
                acc[t] += (zr_[0] + zr_[1]) + (zr_[2] + zr_[3]);
                #pragma unroll
                for (int i = 0; i < 4; ++i) {
                    float nr = zr_[i] * ex_[i] - zi_[i] * ey_[i];
                    zi_[i]   = zr_[i] * ey_[i] + zi_[i] * ex_[i];
                    zr_[i]   = nr;
                }
            }
        }

        float* ob = out + (size_t)b * TOUT * DDIM + d0 + dd;
        if (t0 < 96) {
            #pragma unroll
            for (int t = 0; t < 8; ++t) {
                ob[(size_t)(t0 + t) * DDIM]       = acc[t];
                ob[(size_t)(t0 + t + 512) * DDIM] = acc[t];
            }
        } else {
            #pragma unroll
            for (int t = 0; t < 8; ++t)
                ob[(size_t)(t0 + t) * DDIM] = acc[t];
        }
    }
}

extern "C" void kernel_launch(void* const* d_in, const int* in_sizes, int n_in,
                              void* d_out, int out_size, void* d_ws, size_t ws_size,
                              hipStream_t stream) {
    const float* x   = (const float*)d_in[0];
    float*       out = (float*)d_out;
    fourier_fused<<<BATCH * 64, 512, 0, stream>>>(x, out);
}

// Round 8
// 35.573 us; speedup vs baseline: 1.0232x; 1.0232x over previous
//
#include <hip/hip_runtime.h>
#include <math.h>

#define BATCH 8
#define TLEN  512
#define DDIM  512
#define TOUT  608   // 512 + 96
#define KSEL  32
#define DT    8     // d columns per block in k1

#define TWO_PI_OVER_512 0.0122718463030851562f
#define SC (2.0f / 512.0f)

typedef __attribute__((ext_vector_type(8))) short short8;
typedef __attribute__((ext_vector_type(4))) float f32x4;

// ws layout (bytes):
//   BmT: [8][512 d][512 k2] ushort(bf16)  at 0        (4,194,304 B)
//   Wk : [512 t][512 k2]   ushort(bf16)  at 4194304  (524,288 B)
#define BMT_OFF 0
#define WK_OFF  4194304

__device__ __forceinline__ unsigned short f2bf(float f) {
    unsigned u = __float_as_uint(f);
    return (unsigned short)((u + 0x7FFF + ((u >> 16) & 1)) >> 16);   // RNE
}

// 16-point DFT twiddles (exact constants), e^{-2pi i n/16} = CC[n] - i*SS[n]
__device__ __constant__ const float CC16[16] = {
     1.f,  0.92387953251128674f,  0.70710678118654752f,  0.38268343236508977f,
     0.f, -0.38268343236508977f, -0.70710678118654752f, -0.92387953251128674f,
    -1.f, -0.92387953251128674f, -0.70710678118654752f, -0.38268343236508977f,
     0.f,  0.38268343236508977f,  0.70710678118654752f,  0.92387953251128674f };
__device__ __constant__ const float SS16[16] = {
     0.f,  0.38268343236508977f,  0.70710678118654752f,  0.92387953251128674f,
     1.f,  0.92387953251128674f,  0.70710678118654752f,  0.38268343236508977f,
     0.f, -0.38268343236508977f, -0.70710678118654752f, -0.92387953251128674f,
    -1.f, -0.92387953251128674f, -0.70710678118654752f, -0.38268343236508977f };

// ---------------------------------------------------------------------------
// Kernel W: Wk[t][2m] = bf16(sc*cos(2pi m t/512)), [2m+1] = bf16(-sc*sin(...))
// ---------------------------------------------------------------------------
__global__ __launch_bounds__(256) void wbuild_kernel(unsigned short* __restrict__ Wk) {
    const int t = blockIdx.x;        // 0..511
    const int m = threadIdx.x;       // 0..255
    float s, c;
    sincosf((float)((t * m) & 511) * TWO_PI_OVER_512, &s, &c);
    unsigned val = (unsigned)f2bf(c * SC) | ((unsigned)f2bf(-s * SC) << 16);
    *(unsigned*)&Wk[(size_t)t * 512 + 2 * m] = val;
}

// ---------------------------------------------------------------------------
// Kernel 1: FFT (radix 16x32) + top-32 + emit masked bf16 spectrum BmT[d][k2].
// Identical stage A/B/topk structure to the verified R6 kernel.
// ---------------------------------------------------------------------------
__global__ __launch_bounds__(512, 4) void fft_topk_kernel(const float* __restrict__ x,
                                                          unsigned short* __restrict__ BmT) {
    __shared__ float2 Xl[DT][257];                 // 16,448 B
    __shared__ float  ysr[16 * 33 * 9];            // 19,008 B
    __shared__ float  ysi[16 * 33 * 9];            // 19,008 B

    const int tid = threadIdx.x;
    const int bid = blockIdx.x;          // 8b x 64 d-tiles
    const int b   = bid >> 6;
    const int d0  = (bid & 63) * DT;

    // ---- stage A: thread = (aA, dA, h) computes q rows [8h, 8h+8) ----
    {
        const int h   = tid >> 8;
        const int rem = tid & 255;
        const int aA  = rem >> 3;        // 0..31
        const int dA  = rem & 7;
        const float* xb = x + ((size_t)b * TLEN + aA) * DDIM + d0 + dA;
        float xv[16];
        #pragma unroll
        for (int c = 0; c < 16; ++c)
            xv[c] = xb[(size_t)c * 32 * DDIM];

        #pragma unroll
        for (int qn = 0; qn < 8; ++qn) {
            const int q = qn + 8 * h;
            float sr = 0.f, si = 0.f;
            #pragma unroll
            for (int c = 0; c < 16; ++c) {
                const int n = (c * q) & 15;
                sr = fmaf(xv[c],  CC16[n], sr);
                si = fmaf(xv[c], -SS16[n], si);
            }
            ysr[(q * 33 + aA) * 9 + dA] = sr;
            ysi[(q * 33 + aA) * 9 + dA] = si;
        }
    }
    __syncthreads();

    // ---- stage B: thread = (ahalf, dB, kk) ----
    {
        const int ahalf = tid & 1;
        const int dB    = (tid >> 1) & 7;
        const int kk    = tid >> 4;      // 0..31
        const int qq    = kk & 15;

        float Pr, Pi;
        if (ahalf == 0) { Pr = 1.f; Pi = 0.f; }
        else {
            float s, c;
            sincosf((float)((16 * kk) & 511) * TWO_PI_OVER_512, &s, &c);
            Pr = c; Pi = -s;
        }
        float sts, stc;
        sincosf((float)kk * TWO_PI_OVER_512, &sts, &stc);  // e^{-2pi i kk/512}

        float ar[8] = {}, ai[8] = {};
        #pragma unroll
        for (int aa = 0; aa < 16; ++aa) {
            const int arow = ahalf * 16 + aa;     // (arow*u)&15 == (aa*u)&15
            float Yr = ysr[(qq * 33 + arow) * 9 + dB];
            float Yi = ysi[(qq * 33 + arow) * 9 + dB];
            float zr = Yr * Pr - Yi * Pi;
            float zi = Yr * Pi + Yi * Pr;
            #pragma unroll
            for (int u = 0; u < 8; ++u) {
                const int n = (aa * u) & 15;
                ar[u] = fmaf(zr, CC16[n], fmaf(zi,  SS16[n], ar[u]));
                ai[u] = fmaf(zi, CC16[n], fmaf(-zr, SS16[n], ai[u]));
            }
            float npr = fmaf(Pr, stc,  Pi * sts);
            Pi        = fmaf(Pi, stc, -Pr * sts);
            Pr        = npr;
        }

        #pragma unroll
        for (int u = 0; u < 8; ++u) {
            ar[u] += __shfl_xor(ar[u], 1);
            ai[u] += __shfl_xor(ai[u], 1);
        }
        #pragma unroll
        for (int v = 0; v < 4; ++v) {
            const int u = ahalf * 4 + v;
            Xl[dB][kk + 32 * u] = make_float2(ar[u], ai[u]);
        }
    }
    __syncthreads();   // Xl complete

    // ---- topk: wave w handles column w; emit masked bf16 rows ----
    {
        const int l  = tid & 63;
        const int dd = tid >> 6;         // 0..7
        const unsigned long long below = ((unsigned long long)1 << l) - 1;

        float zr[4], zi[4];
        unsigned vb[4];
        int mm[4];
        #pragma unroll
        for (int s = 0; s < 4; ++s) {
            int m = 1 + l + 64 * s;
            mm[s] = m;
            if (m <= 255) {
                float2 z = Xl[dd][m];
                zr[s] = z.x; zi[s] = z.y;
                vb[s] = __float_as_uint(fmaf(z.x, z.x, z.y * z.y));
            } else { zr[s] = 0.f; zi[s] = 0.f; vb[s] = 0u; }
        }

        unsigned tau = 0;
        for (int bit = 30; bit >= 0; --bit) {
            unsigned cand = tau | (1u << bit);
            int cnt = __popcll(__ballot(vb[0] >= cand))
                    + __popcll(__ballot(vb[1] >= cand))
                    + __popcll(__ballot(vb[2] >= cand))
                    + __popcll(__ballot(vb[3] >= cand));
            if (cnt >= KSEL) tau = cand;
        }

        unsigned long long beq[4];
        int cgt = 0;
        #pragma unroll
        for (int s = 0; s < 4; ++s) {
            beq[s] = __ballot(vb[s] == tau);
            cgt += __popcll(__ballot(vb[s] > tau));
        }
        const int need = KSEL - cgt;     // ties taken at == tau

        unsigned short* Brow = BmT + ((size_t)(b * DDIM + d0 + dd) << 9);
        int be = 0;
        #pragma unroll
        for (int s = 0; s < 4; ++s) {
            bool keep = (vb[s] > tau);
            if (vb[s] == tau) {
                int r = be + __popcll(beq[s] & below);
                keep = (r < need);
            }
            be += __popcll(beq[s]);
            unsigned val = keep ? ((unsigned)f2bf(zr[s]) | ((unsigned)f2bf(zi[s]) << 16)) : 0u;
            int mi = mm[s] & 255;        // m=256 lane remaps to k2 rows 0..1 (zeros)
            *(unsigned*)(Brow + 2 * mi) = val;
        }
    }
}

// ---------------------------------------------------------------------------
// Kernel 2: out[b] = Wk @ BmT[b]^T via MFMA 16x16x32 bf16.
// Block: 64t x 64d tile, 512 threads (8 waves as 4(M) x 2(N), wave = 16t x 32d).
// K = 512 in 8 chunks of 64. Rows 0..95 duplicated to 512..607.
// ---------------------------------------------------------------------------
__global__ __launch_bounds__(512, 4) void gemm_kernel(const unsigned short* __restrict__ Wk,
                                                      const unsigned short* __restrict__ BmT,
                                                      float* __restrict__ out) {
    __shared__ unsigned short Al[64][72];   // pad 72 vs bank conflicts
    __shared__ unsigned short Bl[64][72];

    const int tid = threadIdx.x;
    const int bid = blockIdx.x;          // 8b x 8bt x 8bd
    const int b   = bid >> 6;
    const int bt  = (bid >> 3) & 7;
    const int bd  = bid & 7;

    const int wid  = tid >> 6;           // 0..7
    const int l    = tid & 63;
    const int wm   = wid & 3;            // t-slice of 16
    const int wn   = wid >> 2;           // d-slice of 32
    const int lrow = l & 15;
    const int lk8  = (l >> 4) * 8;

    const int srow = tid >> 3;           // 0..63 staging row
    const int soff = (tid & 7) * 8;      // ushort offset (16 B)

    const unsigned short* Wrow = Wk  + (size_t)(bt * 64 + srow) * 512 + soff;
    const unsigned short* Brow = BmT + ((size_t)(b * DDIM + bd * 64 + srow)) * 512 + soff;

    f32x4 acc0 = {0.f, 0.f, 0.f, 0.f};
    f32x4 acc1 = {0.f, 0.f, 0.f, 0.f};

    for (int kc = 0; kc < 512; kc += 64) {
        uint4 av = *(const uint4*)(Wrow + kc);
        uint4 bv = *(const uint4*)(Brow + kc);
        __syncthreads();                 // previous chunk's reads complete
        *(uint4*)&Al[srow][soff] = av;
        *(uint4*)&Bl[srow][soff] = bv;
        __syncthreads();

        #pragma unroll
        for (int ks = 0; ks < 2; ++ks) {
            short8 af  = *(const short8*)&Al[wm * 16 + lrow][ks * 32 + lk8];
            short8 bf0 = *(const short8*)&Bl[wn * 32 + lrow][ks * 32 + lk8];
            short8 bf1 = *(const short8*)&Bl[wn * 32 + 16 + lrow][ks * 32 + lk8];
            acc0 = __builtin_amdgcn_mfma_f32_16x16x32_bf16(af, bf0, acc0, 0, 0, 0);
            acc1 = __builtin_amdgcn_mfma_f32_16x16x32_bf16(af, bf1, acc1, 0, 0, 0);
        }
    }

    const int tg = bt * 64 + wm * 16 + (l >> 4) * 4;
    const int dg = bd * 64 + wn * 32 + (l & 15);
    float* ob = out + (size_t)b * TOUT * DDIM;
    #pragma unroll
    for (int r = 0; r < 4; ++r) {
        const int t = tg + r;
        ob[(size_t)t * DDIM + dg]      = acc0[r];
        ob[(size_t)t * DDIM + dg + 16] = acc1[r];
        if (t < 96) {
            ob[(size_t)(t + 512) * DDIM + dg]      = acc0[r];
            ob[(size_t)(t + 512) * DDIM + dg + 16] = acc1[r];
        }
    }
}

extern "C" void kernel_launch(void* const* d_in, const int* in_sizes, int n_in,
                              void* d_out, int out_size, void* d_ws, size_t ws_size,
                              hipStream_t stream) {
    const float* x   = (const float*)d_in[0];
    float*       out = (float*)d_out;
    unsigned short* BmT = (unsigned short*)((char*)d_ws + BMT_OFF);
    unsigned short* Wk  = (unsigned short*)((char*)d_ws + WK_OFF);

    wbuild_kernel<<<512, 256, 0, stream>>>(Wk);
    fft_topk_kernel<<<BATCH * 64, 512, 0, stream>>>(x, BmT);
    gemm_kernel<<<BATCH * 64, 512, 0, stream>>>(Wk, BmT, out);
}

// Round 9
// 30.281 us; speedup vs baseline: 1.2020x; 1.1747x over previous
//
#include <hip/hip_runtime.h>
#include <math.h>

#define BATCH 8
#define TLEN  512
#define DDIM  512
#define TOUT  608   // 512 + 96
#define KSEL  32
#define DT    8     // d columns per block in k1

#define TWO_PI_OVER_512 0.0122718463030851562f
#define SC (2.0f / 512.0f)

typedef __attribute__((ext_vector_type(8))) short short8;
typedef __attribute__((ext_vector_type(4))) float f32x4;

// ws layout (bytes):
//   BmT: [8][512 d][512 k2] ushort(bf16)  at 0        (4,194,304 B)
//   Wk : [512 t][512 k2]   ushort(bf16)  at 4194304  (524,288 B)
#define BMT_OFF 0
#define WK_OFF  4194304

__device__ __forceinline__ unsigned short f2bf(float f) {
    unsigned u = __float_as_uint(f);
    return (unsigned short)((u + 0x7FFF + ((u >> 16) & 1)) >> 16);   // RNE
}

// 16-point DFT twiddles (exact constants), e^{-2pi i n/16} = CC[n] - i*SS[n]
__device__ __constant__ const float CC16[16] = {
     1.f,  0.92387953251128674f,  0.70710678118654752f,  0.38268343236508977f,
     0.f, -0.38268343236508977f, -0.70710678118654752f, -0.92387953251128674f,
    -1.f, -0.92387953251128674f, -0.70710678118654752f, -0.38268343236508977f,
     0.f,  0.38268343236508977f,  0.70710678118654752f,  0.92387953251128674f };
__device__ __constant__ const float SS16[16] = {
     0.f,  0.38268343236508977f,  0.70710678118654752f,  0.92387953251128674f,
     1.f,  0.92387953251128674f,  0.70710678118654752f,  0.38268343236508977f,
     0.f, -0.38268343236508977f, -0.70710678118654752f, -0.92387953251128674f,
    -1.f, -0.92387953251128674f, -0.70710678118654752f, -0.38268343236508977f };

// ---------------------------------------------------------------------------
// Kernel 1: FFT (radix 16x32) + top-32 + emit masked bf16 spectrum BmT[d][k2].
// Each block also emits one Wk t-row (grid == 512 == TLEN rows):
//   Wk[t][2m] = bf16(SC*cos(2pi m t/512)), [2m+1] = bf16(-SC*sin(...)).
// Twiddles come from the in-LDS table tw[512]; one sincosf per thread total.
// ---------------------------------------------------------------------------
__global__ __launch_bounds__(512, 4) void fft_topk_kernel(const float* __restrict__ x,
                                                          unsigned short* __restrict__ BmT,
                                                          unsigned short* __restrict__ Wk) {
    __shared__ float2 Xl[DT][257];                 // 16,448 B
    __shared__ float  ysr[16 * 33 * 9];            // 19,008 B
    __shared__ float  ysi[16 * 33 * 9];            // 19,008 B
    __shared__ float2 tw[512];                     // 4,096 B

    const int tid = threadIdx.x;
    const int bid = blockIdx.x;          // 8b x 64 d-tiles (== 512 t-rows for Wk)
    const int b   = bid >> 6;
    const int d0  = (bid & 63) * DT;

    {   // twiddle table: tw[n] = (cos, sin)(2 pi n / 512)
        float s, c;
        sincosf((float)tid * TWO_PI_OVER_512, &s, &c);
        tw[tid] = make_float2(c, s);
    }

    // ---- stage A: thread = (aA, dA, h) computes q rows [8h, 8h+8) ----
    {
        const int h   = tid >> 8;
        const int rem = tid & 255;
        const int aA  = rem >> 3;        // 0..31
        const int dA  = rem & 7;
        const float* xb = x + ((size_t)b * TLEN + aA) * DDIM + d0 + dA;
        float xv[16];
        #pragma unroll
        for (int c = 0; c < 16; ++c)
            xv[c] = xb[(size_t)c * 32 * DDIM];

        #pragma unroll
        for (int qn = 0; qn < 8; ++qn) {
            const int q = qn + 8 * h;
            float sr = 0.f, si = 0.f;
            #pragma unroll
            for (int c = 0; c < 16; ++c) {
                const int n = (c * q) & 15;
                sr = fmaf(xv[c],  CC16[n], sr);
                si = fmaf(xv[c], -SS16[n], si);
            }
            ysr[(q * 33 + aA) * 9 + dA] = sr;
            ysi[(q * 33 + aA) * 9 + dA] = si;
        }
    }
    __syncthreads();   // ys + tw ready

    // ---- stage B: thread = (ahalf, dB, kk) ----
    {
        const int ahalf = tid & 1;
        const int dB    = (tid >> 1) & 7;
        const int kk    = tid >> 4;      // 0..31
        const int qq    = kk & 15;

        float Pr, Pi;
        if (ahalf == 0) { Pr = 1.f; Pi = 0.f; }
        else {
            float2 w = tw[(16 * kk) & 511];
            Pr = w.x; Pi = -w.y;
        }
        const float2 w2 = tw[kk];        // e^{-2pi i kk/512} = (w2.x, -w2.y)
        const float stc = w2.x, sts = w2.y;

        float ar[8] = {}, ai[8] = {};
        #pragma unroll
        for (int aa = 0; aa < 16; ++aa) {
            const int arow = ahalf * 16 + aa;     // (arow*u)&15 == (aa*u)&15
            float Yr = ysr[(qq * 33 + arow) * 9 + dB];
            float Yi = ysi[(qq * 33 + arow) * 9 + dB];
            float zr = Yr * Pr - Yi * Pi;
            float zi = Yr * Pi + Yi * Pr;
            #pragma unroll
            for (int u = 0; u < 8; ++u) {
                const int n = (aa * u) & 15;
                ar[u] = fmaf(zr, CC16[n], fmaf(zi,  SS16[n], ar[u]));
                ai[u] = fmaf(zi, CC16[n], fmaf(-zr, SS16[n], ai[u]));
            }
            float npr = fmaf(Pr, stc,  Pi * sts);
            Pi        = fmaf(Pi, stc, -Pr * sts);
            Pr        = npr;
        }

        #pragma unroll
        for (int u = 0; u < 8; ++u) {
            ar[u] += __shfl_xor(ar[u], 1);
            ai[u] += __shfl_xor(ai[u], 1);
        }
        #pragma unroll
        for (int v = 0; v < 4; ++v) {
            const int u = ahalf * 4 + v;
            Xl[dB][kk + 32 * u] = make_float2(ar[u], ai[u]);
        }
    }
    __syncthreads();   // Xl complete

    // ---- Wk row emission: t = bid, m = tid (waves 0..3 only) ----
    if (tid < 256) {
        float2 w = tw[(bid * tid) & 511];
        unsigned val = (unsigned)f2bf(w.x * SC) | ((unsigned)f2bf(-w.y * SC) << 16);
        *(unsigned*)&Wk[((size_t)bid << 9) + 2 * tid] = val;
    }

    // ---- topk: wave w handles column w; emit masked bf16 rows ----
    {
        const int l  = tid & 63;
        const int dd = tid >> 6;         // 0..7
        const unsigned long long below = ((unsigned long long)1 << l) - 1;

        float zr[4], zi[4];
        unsigned vb[4];
        int mm[4];
        #pragma unroll
        for (int s = 0; s < 4; ++s) {
            int m = 1 + l + 64 * s;
            mm[s] = m;
            if (m <= 255) {
                float2 z = Xl[dd][m];
                zr[s] = z.x; zi[s] = z.y;
                vb[s] = __float_as_uint(fmaf(z.x, z.x, z.y * z.y));
            } else { zr[s] = 0.f; zi[s] = 0.f; vb[s] = 0u; }
        }

        unsigned tau = 0;
        for (int bit = 30; bit >= 0; --bit) {
            unsigned cand = tau | (1u << bit);
            int cnt = __popcll(__ballot(vb[0] >= cand))
                    + __popcll(__ballot(vb[1] >= cand))
                    + __popcll(__ballot(vb[2] >= cand))
                    + __popcll(__ballot(vb[3] >= cand));
            if (cnt >= KSEL) tau = cand;
        }

        unsigned long long beq[4];
        int cgt = 0;
        #pragma unroll
        for (int s = 0; s < 4; ++s) {
            beq[s] = __ballot(vb[s] == tau);
            cgt += __popcll(__ballot(vb[s] > tau));
        }
        const int need = KSEL - cgt;     // ties taken at == tau

        unsigned short* Brow = BmT + ((size_t)(b * DDIM + d0 + dd) << 9);
        int be = 0;
        #pragma unroll
        for (int s = 0; s < 4; ++s) {
            bool keep = (vb[s] > tau);
            if (vb[s] == tau) {
                int r = be + __popcll(beq[s] & below);
                keep = (r < need);
            }
            be += __popcll(beq[s]);
            unsigned val = keep ? ((unsigned)f2bf(zr[s]) | ((unsigned)f2bf(zi[s]) << 16)) : 0u;
            int mi = mm[s] & 255;        // m=256 lane remaps to k2 rows 0..1 (zeros)
            *(unsigned*)(Brow + 2 * mi) = val;
        }
    }
}

// ---------------------------------------------------------------------------
// Kernel 2: out[b] = Wk @ BmT[b]^T via MFMA 16x16x32 bf16.
// Block: 64t x 64d tile, 512 threads (8 waves as 4(M) x 2(N), wave = 16t x 32d).
// K = 512 in 8 chunks of 64. Rows 0..95 duplicated to 512..607.
// ---------------------------------------------------------------------------
__global__ __launch_bounds__(512, 4) void gemm_kernel(const unsigned short* __restrict__ Wk,
                                                      const unsigned short* __restrict__ BmT,
                                                      float* __restrict__ out) {
    __shared__ unsigned short Al[64][72];   // pad 72 vs bank conflicts
    __shared__ unsigned short Bl[64][72];

    const int tid = threadIdx.x;
    const int bid = blockIdx.x;          // 8b x 8bt x 8bd
    const int b   = bid >> 6;
    const int bt  = (bid >> 3) & 7;
    const int bd  = bid & 7;

    const int wid  = tid >> 6;           // 0..7
    const int l    = tid & 63;
    const int wm   = wid & 3;            // t-slice of 16
    const int wn   = wid >> 2;           // d-slice of 32
    const int lrow = l & 15;
    const int lk8  = (l >> 4) * 8;

    const int srow = tid >> 3;           // 0..63 staging row
    const int soff = (tid & 7) * 8;      // ushort offset (16 B)

    const unsigned short* Wrow = Wk  + (size_t)(bt * 64 + srow) * 512 + soff;
    const unsigned short* Brow = BmT + ((size_t)(b * DDIM + bd * 64 + srow)) * 512 + soff;

    f32x4 acc0 = {0.f, 0.f, 0.f, 0.f};
    f32x4 acc1 = {0.f, 0.f, 0.f, 0.f};

    for (int kc = 0; kc < 512; kc += 64) {
        uint4 av = *(const uint4*)(Wrow + kc);
        uint4 bv = *(const uint4*)(Brow + kc);
        __syncthreads();                 // previous chunk's reads complete
        *(uint4*)&Al[srow][soff] = av;
        *(uint4*)&Bl[srow][soff] = bv;
        __syncthreads();

        #pragma unroll
        for (int ks = 0; ks < 2; ++ks) {
            short8 af  = *(const short8*)&Al[wm * 16 + lrow][ks * 32 + lk8];
            short8 bf0 = *(const short8*)&Bl[wn * 32 + lrow][ks * 32 + lk8];
            short8 bf1 = *(const short8*)&Bl[wn * 32 + 16 + lrow][ks * 32 + lk8];
            acc0 = __builtin_amdgcn_mfma_f32_16x16x32_bf16(af, bf0, acc0, 0, 0, 0);
            acc1 = __builtin_amdgcn_mfma_f32_16x16x32_bf16(af, bf1, acc1, 0, 0, 0);
        }
    }

    const int tg = bt * 64 + wm * 16 + (l >> 4) * 4;
    const int dg = bd * 64 + wn * 32 + (l & 15);
    float* ob = out + (size_t)b * TOUT * DDIM;
    #pragma unroll
    for (int r = 0; r < 4; ++r) {
        const int t = tg + r;
        ob[(size_t)t * DDIM + dg]      = acc0[r];
        ob[(size_t)t * DDIM + dg + 16] = acc1[r];
        if (t < 96) {
            ob[(size_t)(t + 512) * DDIM + dg]      = acc0[r];
            ob[(size_t)(t + 512) * DDIM + dg + 16] = acc1[r];
        }
    }
}

extern "C" void kernel_launch(void* const* d_in, const int* in_sizes, int n_in,
                              void* d_out, int out_size, void* d_ws, size_t ws_size,
                              hipStream_t stream) {
    const float* x   = (const float*)d_in[0];
    float*       out = (float*)d_out;
    unsigned short* BmT = (unsigned short*)((char*)d_ws + BMT_OFF);
    unsigned short* Wk  = (unsigned short*)((char*)d_ws + WK_OFF);

    fft_topk_kernel<<<BATCH * 64, 512, 0, stream>>>(x, BmT, Wk);
    gemm_kernel<<<BATCH * 64, 512, 0, stream>>>(Wk, BmT, out);
}

// Round 11
// 27.154 us; speedup vs baseline: 1.3405x; 1.1152x over previous
//
#include <hip/hip_runtime.h>
#include <math.h>

#define BATCH 8
#define TLEN  512
#define DDIM  512
#define TOUT  608   // 512 + 96
#define KSEL  32
#define DT    8     // d columns per block in k1

#define TWO_PI_OVER_512 0.0122718463030851562f
#define SC (2.0f / 512.0f)

typedef __attribute__((ext_vector_type(8))) short short8;
typedef __attribute__((ext_vector_type(4))) float f32x4;

// ws layout (bytes):
//   BmT: [8][512 d][512 k2] ushort(bf16)  at 0        (4,194,304 B)
//   Wk : [512 t][512 k2]   ushort(bf16)  at 4194304  (524,288 B)
#define BMT_OFF 0
#define WK_OFF  4194304

__device__ __forceinline__ unsigned short f2bf(float f) {
    unsigned u = __float_as_uint(f);
    return (unsigned short)((u + 0x7FFF + ((u >> 16) & 1)) >> 16);   // RNE
}

// 16-point DFT twiddles (exact constants), e^{-2pi i n/16} = CC[n] - i*SS[n]
__device__ __constant__ const float CC16[16] = {
     1.f,  0.92387953251128674f,  0.70710678118654752f,  0.38268343236508977f,
     0.f, -0.38268343236508977f, -0.70710678118654752f, -0.92387953251128674f,
    -1.f, -0.92387953251128674f, -0.70710678118654752f, -0.38268343236508977f,
     0.f,  0.38268343236508977f,  0.70710678118654752f,  0.92387953251128674f };
__device__ __constant__ const float SS16[16] = {
     0.f,  0.38268343236508977f,  0.70710678118654752f,  0.92387953251128674f,
     1.f,  0.92387953251128674f,  0.70710678118654752f,  0.38268343236508977f,
     0.f, -0.38268343236508977f, -0.70710678118654752f, -0.92387953251128674f,
    -1.f, -0.92387953251128674f, -0.70710678118654752f, -0.38268343236508977f };

// ---------------------------------------------------------------------------
// Kernel 1: FFT (radix 16x32) + top-32 + emit masked bf16 spectrum BmT[d][k2].
// XCD swizzle: dtile = 8*(bid&7) + ((bid>>3)&7), b = bid>>6  -> each XCD owns
// 8 contiguous d-tiles (64 consecutive d), so every 64B x-line is consumed
// within one XCD's L2 (kills the 2x HBM overfetch from DT=8 < 16-float lines).
// Each block also emits one Wk t-row (t = bid):
//   Wk[t][2m] = bf16(SC*cos(2pi m t/512)), [2m+1] = bf16(-SC*sin(...)).
// ---------------------------------------------------------------------------
__global__ __launch_bounds__(512, 4) void fft_topk_kernel(const float* __restrict__ x,
                                                          unsigned short* __restrict__ BmT,
                                                          unsigned short* __restrict__ Wk) {
    __shared__ float2 Xl[DT][257];                 // 16,448 B
    __shared__ float  ysr[16 * 33 * 9];            // 19,008 B
    __shared__ float  ysi[16 * 33 * 9];            // 19,008 B
    __shared__ float2 tw[512];                     // 4,096 B

    const int tid = threadIdx.x;
    const int bid = blockIdx.x;
    const int b   = bid >> 6;
    const int d0  = ((bid & 7) * 8 + ((bid >> 3) & 7)) * DT;   // XCD-contiguous d

    {   // twiddle table: tw[n] = (cos, sin)(2 pi n / 512)
        float s, c;
        sincosf((float)tid * TWO_PI_OVER_512, &s, &c);
        tw[tid] = make_float2(c, s);
    }

    // ---- stage A: thread = (aA, dA, h) computes q rows [8h, 8h+8) ----
    {
        const int h   = tid >> 8;
        const int rem = tid & 255;
        const int aA  = rem >> 3;        // 0..31
        const int dA  = rem & 7;
        const float* xb = x + ((size_t)b * TLEN + aA) * DDIM + d0 + dA;
        float xv[16];
        #pragma unroll
        for (int c = 0; c < 16; ++c)
            xv[c] = xb[(size_t)c * 32 * DDIM];

        #pragma unroll
        for (int qn = 0; qn < 8; ++qn) {
            const int q = qn + 8 * h;
            float sr = 0.f, si = 0.f;
            #pragma unroll
            for (int c = 0; c < 16; ++c) {
                const int n = (c * q) & 15;
                sr = fmaf(xv[c],  CC16[n], sr);
                si = fmaf(xv[c], -SS16[n], si);
            }
            ysr[(q * 33 + aA) * 9 + dA] = sr;
            ysi[(q * 33 + aA) * 9 + dA] = si;
        }
    }
    __syncthreads();   // ys + tw ready

    // ---- stage B: thread = (ahalf, dB, kk) ----
    {
        const int ahalf = tid & 1;
        const int dB    = (tid >> 1) & 7;
        const int kk    = tid >> 4;      // 0..31
        const int qq    = kk & 15;

        float Pr, Pi;
        if (ahalf == 0) { Pr = 1.f; Pi = 0.f; }
        else {
            float2 w = tw[(16 * kk) & 511];
            Pr = w.x; Pi = -w.y;
        }
        const float2 w2 = tw[kk];        // e^{-2pi i kk/512} = (w2.x, -w2.y)
        const float stc = w2.x, sts = w2.y;

        float ar[8] = {}, ai[8] = {};
        #pragma unroll
        for (int aa = 0; aa < 16; ++aa) {
            const int arow = ahalf * 16 + aa;     // (arow*u)&15 == (aa*u)&15
            float Yr = ysr[(qq * 33 + arow) * 9 + dB];
            float Yi = ysi[(qq * 33 + arow) * 9 + dB];
            float zr = Yr * Pr - Yi * Pi;
            float zi = Yr * Pi + Yi * Pr;
            #pragma unroll
            for (int u = 0; u < 8; ++u) {
                const int n = (aa * u) & 15;
                ar[u] = fmaf(zr, CC16[n], fmaf(zi,  SS16[n], ar[u]));
                ai[u] = fmaf(zi, CC16[n], fmaf(-zr, SS16[n], ai[u]));
            }
            float npr = fmaf(Pr, stc,  Pi * sts);
            Pi        = fmaf(Pi, stc, -Pr * sts);
            Pr        = npr;
        }

        #pragma unroll
        for (int u = 0; u < 8; ++u) {
            ar[u] += __shfl_xor(ar[u], 1);
            ai[u] += __shfl_xor(ai[u], 1);
        }
        #pragma unroll
        for (int v = 0; v < 4; ++v) {
            const int u = ahalf * 4 + v;
            Xl[dB][kk + 32 * u] = make_float2(ar[u], ai[u]);
        }
    }
    __syncthreads();   // Xl complete

    // ---- Wk row emission: t = bid, m = tid (waves 0..3 only) ----
    if (tid < 256) {
        float2 w = tw[(bid * tid) & 511];
        unsigned val = (unsigned)f2bf(w.x * SC) | ((unsigned)f2bf(-w.y * SC) << 16);
        *(unsigned*)&Wk[((size_t)bid << 9) + 2 * tid] = val;
    }

    // ---- topk: wave w handles column w; emit masked bf16 rows ----
    {
        const int l  = tid & 63;
        const int dd = tid >> 6;         // 0..7
        const unsigned long long below = ((unsigned long long)1 << l) - 1;

        float zr[4], zi[4];
        unsigned vb[4];
        int mm[4];
        #pragma unroll
        for (int s = 0; s < 4; ++s) {
            int m = 1 + l + 64 * s;
            mm[s] = m;
            if (m <= 255) {
                float2 z = Xl[dd][m];
                zr[s] = z.x; zi[s] = z.y;
                vb[s] = __float_as_uint(fmaf(z.x, z.x, z.y * z.y));
            } else { zr[s] = 0.f; zi[s] = 0.f; vb[s] = 0u; }
        }

        unsigned tau = 0;
        for (int bit = 30; bit >= 0; --bit) {
            unsigned cand = tau | (1u << bit);
            int cnt = __popcll(__ballot(vb[0] >= cand))
                    + __popcll(__ballot(vb[1] >= cand))
                    + __popcll(__ballot(vb[2] >= cand))
                    + __popcll(__ballot(vb[3] >= cand));
            if (cnt >= KSEL) tau = cand;
        }

        unsigned long long beq[4];
        int cgt = 0;
        #pragma unroll
        for (int s = 0; s < 4; ++s) {
            beq[s] = __ballot(vb[s] == tau);
            cgt += __popcll(__ballot(vb[s] > tau));
        }
        const int need = KSEL - cgt;     // ties taken at == tau

        unsigned short* Brow = BmT + ((size_t)(b * DDIM + d0 + dd) << 9);
        int be = 0;
        #pragma unroll
        for (int s = 0; s < 4; ++s) {
            bool keep = (vb[s] > tau);
            if (vb[s] == tau) {
                int r = be + __popcll(beq[s] & below);
                keep = (r < need);
            }
            be += __popcll(beq[s]);
            unsigned val = keep ? ((unsigned)f2bf(zr[s]) | ((unsigned)f2bf(zi[s]) << 16)) : 0u;
            int mi = mm[s] & 255;        // m=256 lane remaps to k2 rows 0..1 (zeros)
            *(unsigned*)(Brow + 2 * mi) = val;
        }
    }
}

// ---------------------------------------------------------------------------
// Kernel 2: out[b] = Wk @ BmT[b]^T via MFMA 16x16x32 bf16.
// XCD swizzle: bd = bid&7 -> all 8 readers (bt=0..7) of one BmT slice (b,bd)
// share an XCD, so the 512 KB slice is fetched into that L2 once.
// Block: 64t x 64d tile, 512 threads (8 waves as 4(M) x 2(N)).
// K = 512 in 8 chunks of 64. Rows 0..95 duplicated to 512..607.
// ---------------------------------------------------------------------------
__global__ __launch_bounds__(512, 4) void gemm_kernel(const unsigned short* __restrict__ Wk,
                                                      const unsigned short* __restrict__ BmT,
                                                      float* __restrict__ out) {
    __shared__ unsigned short Al[64][72];   // pad 72 vs bank conflicts
    __shared__ unsigned short Bl[64][72];

    const int tid = threadIdx.x;
    const int bid = blockIdx.x;
    const int bt  = bid >> 6;            // Wk t-tile
    const int b   = (bid >> 3) & 7;
    const int bd  = bid & 7;             // = bid%8 -> XCD id shares BmT slice

    const int wid  = tid >> 6;           // 0..7
    const int l    = tid & 63;
    const int wm   = wid & 3;            // t-slice of 16
    const int wn   = wid >> 2;           // d-slice of 32
    const int lrow = l & 15;
    const int lk8  = (l >> 4) * 8;

    const int srow = tid >> 3;           // 0..63 staging row
    const int soff = (tid & 7) * 8;      // ushort offset (16 B)

    const unsigned short* Wrow = Wk  + (size_t)(bt * 64 + srow) * 512 + soff;
    const unsigned short* Brow = BmT + ((size_t)(b * DDIM + bd * 64 + srow)) * 512 + soff;

    f32x4 acc0 = {0.f, 0.f, 0.f, 0.f};
    f32x4 acc1 = {0.f, 0.f, 0.f, 0.f};

    for (int kc = 0; kc < 512; kc += 64) {
        uint4 av = *(const uint4*)(Wrow + kc);
        uint4 bv = *(const uint4*)(Brow + kc);
        __syncthreads();                 // previous chunk's reads complete
        *(uint4*)&Al[srow][soff] = av;
        *(uint4*)&Bl[srow][soff] = bv;
        __syncthreads();

        #pragma unroll
        for (int ks = 0; ks < 2; ++ks) {
            short8 af  = *(const short8*)&Al[wm * 16 + lrow][ks * 32 + lk8];
            short8 bf0 = *(const short8*)&Bl[wn * 32 + lrow][ks * 32 + lk8];
            short8 bf1 = *(const short8*)&Bl[wn * 32 + 16 + lrow][ks * 32 + lk8];
            acc0 = __builtin_amdgcn_mfma_f32_16x16x32_bf16(af, bf0, acc0, 0, 0, 0);
            acc1 = __builtin_amdgcn_mfma_f32_16x16x32_bf16(af, bf1, acc1, 0, 0, 0);
        }
    }

    const int tg = bt * 64 + wm * 16 + (l >> 4) * 4;
    const int dg = bd * 64 + wn * 32 + (l & 15);
    float* ob = out + (size_t)b * TOUT * DDIM;
    #pragma unroll
    for (int r = 0; r < 4; ++r) {
        const int t = tg + r;
        ob[(size_t)t * DDIM + dg]      = acc0[r];
        ob[(size_t)t * DDIM + dg + 16] = acc1[r];
        if (t < 96) {
            ob[(size_t)(t + 512) * DDIM + dg]      = acc0[r];
            ob[(size_t)(t + 512) * DDIM + dg + 16] = acc1[r];
        }
    }
}

extern "C" void kernel_launch(void* const* d_in, const int* in_sizes, int n_in,
                              void* d_out, int out_size, void* d_ws, size_t ws_size,
                              hipStream_t stream) {
    const float* x   = (const float*)d_in[0];
    float*       out = (float*)d_out;
    unsigned short* BmT = (unsigned short*)((char*)d_ws + BMT_OFF);
    unsigned short* Wk  = (unsigned short*)((char*)d_ws + WK_OFF);

    fft_topk_kernel<<<BATCH * 64, 512, 0, stream>>>(x, BmT, Wk);
    gemm_kernel<<<BATCH * 64, 512, 0, stream>>>(Wk, BmT, out);
}